// Round 1
// baseline (1816.288 us; speedup 1.0000x reference)
//
#include <hip/hip_runtime.h>
#include <cstdint>
#include <cstddef>

// Problem constants: B=8, S=12, N=4096, F=4, H=64
// Encoder: 12x [ adj(4096x4096) @ cat(4096, 768 packed cols) ] via bf16 MFMA
// Gate scramble: flat split of [B, N*3H] into f/i/o (crosses node boundaries).
// Decoder: 12x [32768x64]@[64x256] + fused per-step MLP (hs never materialized).

typedef unsigned short u16;
typedef short s8v __attribute__((ext_vector_type(8)));   // 8 x bf16 bits (4 VGPRs)
typedef float f4v __attribute__((ext_vector_type(4)));   // MFMA accumulator

__device__ __forceinline__ u16 f2bf(float x){
  union { float f; uint32_t u; } v; v.f = x;
  uint32_t r = v.u + 0x7FFFu + ((v.u >> 16) & 1u);   // RNE
  return (u16)(r >> 16);
}
__device__ __forceinline__ float sigm(float x){ return 1.0f / (1.0f + __expf(-x)); }

// C[M][Ncols] = A[M][K] @ Bt[Ncols][K]^T   (bf16 in, fp32 acc, 64x64 tile, BK=32)
// 256 threads = 4 waves in 2x2, each wave 32x32 (2x2 frags of 16x16x32 MFMA).
template<bool BF16OUT>
__global__ __launch_bounds__(256)
void gemm_bt64(const u16* __restrict__ A, const u16* __restrict__ Bt,
               void* __restrict__ C, int M, int Ncols, int K)
{
  __shared__ u16 As[64*32];
  __shared__ u16 Bs[64*32];
  const int t  = threadIdx.x;
  const int l  = t & 63;
  const int w  = t >> 6;
  const int wm = (w >> 1) * 32;
  const int wc = (w & 1) * 32;
  const int mb = blockIdx.x * 64;
  const int nb = blockIdx.y * 64;

  f4v acc[2][2];
  #pragma unroll
  for (int i = 0; i < 2; ++i)
    #pragma unroll
    for (int j = 0; j < 2; ++j) acc[i][j] = (f4v)0.0f;

  // staging: thread t loads one 16B chunk per matrix per iter; row = t>>2, ko = (t&3)*8
  const int srow = t >> 2;
  const int sko  = (t & 3) * 8;
  const u16* ag = A  + (size_t)(mb + srow) * K + sko;
  const u16* bg = Bt + (size_t)(nb + srow) * K + sko;

  for (int k0 = 0; k0 < K; k0 += 32) {
    uint4 av = *(const uint4*)(ag + k0);
    uint4 bv = *(const uint4*)(bg + k0);
    *(uint4*)&As[t * 8] = av;
    *(uint4*)&Bs[t * 8] = bv;
    __syncthreads();
    s8v af[2], bfr[2];
    #pragma unroll
    for (int mt = 0; mt < 2; ++mt)   // A[m=l&15][k=(l>>4)*8+j], m89/m91-verified layout
      af[mt] = *(const s8v*)&As[(wm + mt*16 + (l & 15)) * 32 + (l >> 4) * 8];
    #pragma unroll
    for (int nt = 0; nt < 2; ++nt)
      bfr[nt] = *(const s8v*)&Bs[(wc + nt*16 + (l & 15)) * 32 + (l >> 4) * 8];
    #pragma unroll
    for (int mt = 0; mt < 2; ++mt)
      #pragma unroll
      for (int nt = 0; nt < 2; ++nt)
        acc[mt][nt] = __builtin_amdgcn_mfma_f32_16x16x32_bf16(af[mt], bfr[nt], acc[mt][nt], 0, 0, 0);
    __syncthreads();
  }

  // C/D layout: col = lane&15, row = (lane>>4)*4 + reg  (m89/m91-verified)
  const int colo = l & 15;
  const int rowo = (l >> 4) * 4;
  #pragma unroll
  for (int mt = 0; mt < 2; ++mt)
    #pragma unroll
    for (int nt = 0; nt < 2; ++nt)
      #pragma unroll
      for (int r = 0; r < 4; ++r) {
        int gr = mb + wm + mt*16 + rowo + r;
        int gc = nb + wc + nt*16 + colo;
        if (BF16OUT) ((u16*)C)[(size_t)gr * Ncols + gc] = f2bf(acc[mt][nt][r]);
        else         ((float*)C)[(size_t)gr * Ncols + gc] = acc[mt][nt][r];
      }
}

__global__ void conv_adj(const float* __restrict__ adj, u16* __restrict__ out){
  size_t i = ((size_t)blockIdx.x * 256 + threadIdx.x) * 4;
  float4 v = *(const float4*)(adj + i);
  ushort4 o; o.x = f2bf(v.x); o.y = f2bf(v.y); o.z = f2bf(v.z); o.w = f2bf(v.w);
  *(ushort4*)(out + i) = o;
}

// WT[j][ch] (256x96): ch 0..3 = W1/W2 x-rows, 4..67 = h-rows, 68..95 = 0. j<192 -> W1, else W2.
__global__ void build_w(const float* __restrict__ W1, const float* __restrict__ W2,
                        const float* __restrict__ Wih, const float* __restrict__ Whh,
                        u16* __restrict__ WT, u16* __restrict__ WihB, u16* __restrict__ WhhB){
  int gid = blockIdx.x * 256 + threadIdx.x;
  if (gid < 24576) {
    int j = gid / 96, ch = gid - j * 96;
    float v = 0.0f;
    if (ch < 68) v = (j < 192) ? W1[(size_t)ch * 192 + j] : W2[(size_t)ch * 64 + (j - 192)];
    WT[gid] = f2bf(v);
  } else if (gid < 24576 + 16384) {
    int q = gid - 24576; WihB[q] = f2bf(Wih[q]);
  } else if (gid < 24576 + 32768) {
    int q = gid - 24576 - 16384; WhhB[q] = f2bf(Whh[q]);
  }
}

// PB rows: b*96 + ch; ch 0..3 = x_t (pack_x), 4..67 = h (init: struc_emb), 68..95 = 0
__global__ void init_pb(const float* __restrict__ struc, u16* __restrict__ PB){
  int gid = blockIdx.x * 256 + threadIdx.x;      // 8*92*4096
  int n = gid & 4095;
  int r = gid >> 12;                             // b*92 + (ch-4)
  int b = r / 92, ch = r - b * 92 + 4;
  float v = (ch < 68) ? struc[(size_t)n * 64 + (ch - 4)] : 0.0f;
  PB[((size_t)(b * 96 + ch)) * 4096 + n] = f2bf(v);
}

__global__ void pack_x(const float* __restrict__ X, u16* __restrict__ PB, int tstep){
  int gid = blockIdx.x * 256 + threadIdx.x;      // 8*4*4096
  int n = gid & 4095;
  int c = (gid >> 12) & 3;
  int b = gid >> 14;
  PB[((size_t)(b * 96 + c)) * 4096 + n] =
      f2bf(X[(((size_t)(b * 12 + tstep)) * 4096 + n) * 4 + c]);
}

// pre[r=(n*8+b)][j 0..255]: j<192 -> W1 gates (pre-b1), 192..255 -> conv (pre-b2)
// flat gate split: f=g[k], i=g[k+NH], o=g[k+2NH] with g flat over [N, 192]
__global__ __launch_bounds__(256)
void enc_update(const float* __restrict__ pre, const float* __restrict__ b1,
                const float* __restrict__ b2, const float* __restrict__ struc,
                u16* __restrict__ PB, float* __restrict__ zout,
                u16* __restrict__ zbf, int last)
{
  int gid = blockIdx.x * 256 + threadIdx.x;      // 8 * 262144
  int b = gid >> 18;
  int k = gid & 262143;
  int n = k >> 6, hh = k & 63;
  int qi = k + 262144, qo = k + 524288;
  int nf = k  / 192, jf = k  - nf * 192;
  int ni = qi / 192, ji = qi - ni * 192;
  int no = qo / 192, jo = qo - no * 192;
  float fg = sigm(pre[((size_t)nf * 8 + b) * 256 + jf] + b1[jf]);
  float ig = sigm(pre[((size_t)ni * 8 + b) * 256 + ji] + b1[ji]);
  float og = sigm(pre[((size_t)no * 8 + b) * 256 + jo] + b1[jo]);
  float conv = pre[((size_t)n * 8 + b) * 256 + 192 + hh] + b2[hh];
  float c0 = struc[k];
  float c  = fg * c0 + ig * tanhf(conv);
  float hv = og * tanhf(c);
  PB[((size_t)(b * 96 + 4 + hh)) * 4096 + n] = f2bf(hv);   // transposed for next-step GEMM
  if (last) {
    zout[(size_t)b * 262144 + k] = hv;   // z output [B,N,H] flat
    zbf [(size_t)b * 262144 + k] = f2bf(hv);
  }
}

__global__ void zero_dec(float* __restrict__ cdec, u16* __restrict__ hbf){
  int gid = blockIdx.x * 256 + threadIdx.x;
  cdec[gid] = 0.0f;
  hbf[gid] = 0;
}

// LSTM cell (i,f,g,o torch order) + fused 2-layer MLP -> recon column s
__global__ __launch_bounds__(256)
void dec_update(const float* __restrict__ xg, const float* __restrict__ ghh,
                const float* __restrict__ bih, const float* __restrict__ bhh,
                const float* __restrict__ D1, const float* __restrict__ bd1,
                const float* __restrict__ D2, const float* __restrict__ bd2,
                float* __restrict__ cdec, u16* __restrict__ hbf,
                float* __restrict__ recon, int s)
{
  __shared__ float hl[64][65];   // +1 pad: column reads conflict-free
  const int t = threadIdx.x;
  const size_t r0 = (size_t)blockIdx.x * 64;
  #pragma unroll
  for (int j = 0; j < 16; ++j) {
    int idx = t + 256 * j;               // [64 rows][64 hh]
    int rl = idx >> 6, hh = idx & 63;
    size_t row = r0 + rl;
    size_t gi = row * 256 + hh;
    float ig = sigm (xg[gi      ] + ghh[gi      ] + bih[hh      ] + bhh[hh      ]);
    float fg = sigm (xg[gi +  64] + ghh[gi +  64] + bih[hh +  64] + bhh[hh +  64]);
    float gg = tanhf(xg[gi + 128] + ghh[gi + 128] + bih[hh + 128] + bhh[hh + 128]);
    float og = sigm (xg[gi + 192] + ghh[gi + 192] + bih[hh + 192] + bhh[hh + 192]);
    float c = fg * cdec[row * 64 + hh] + ig * gg;
    float h = og * tanhf(c);
    cdec[row * 64 + hh] = c;
    hbf [row * 64 + hh] = f2bf(h);
    hl[rl][hh] = h;
  }
  __syncthreads();
  if (t < 64) {
    float d = bd2[0];
    for (int jj = 0; jj < 32; ++jj) {
      float m = bd1[jj];
      #pragma unroll 8
      for (int hh = 0; hh < 64; ++hh) m += hl[t][hh] * D1[hh * 32 + jj];
      d += fmaxf(m, 0.0f) * D2[jj];
    }
    recon[(r0 + t) * 12 + s] = d;        // recon flat = d[B*N][S]
  }
}

extern "C" void kernel_launch(void* const* d_in, const int* in_sizes, int n_in,
                              void* d_out, int out_size, void* d_ws, size_t ws_size,
                              hipStream_t stream)
{
  (void)in_sizes; (void)n_in; (void)out_size; (void)ws_size;
  const float* X     = (const float*)d_in[0];
  const float* adj   = (const float*)d_in[1];
  const float* struc = (const float*)d_in[2];
  const float* W1    = (const float*)d_in[3];
  const float* b1    = (const float*)d_in[4];
  const float* W2    = (const float*)d_in[5];
  const float* b2    = (const float*)d_in[6];
  const float* Wih   = (const float*)d_in[7];
  const float* Whh   = (const float*)d_in[8];
  const float* bih   = (const float*)d_in[9];
  const float* bhh   = (const float*)d_in[10];
  const float* D1    = (const float*)d_in[11];
  const float* bd1   = (const float*)d_in[12];
  const float* D2    = (const float*)d_in[13];
  const float* bd2   = (const float*)d_in[14];

  char* ws = (char*)d_ws;
  size_t off = 0;
  auto alloc = [&](size_t bytes){ void* p = ws + off; off += (bytes + 255) & ~(size_t)255; return p; };
  u16*   adj_bf = (u16*)  alloc(4096ull * 4096 * 2);   // 33.5 MB
  u16*   PB     = (u16*)  alloc(768ull * 4096 * 2);    // packed B^T [b*96+ch][n]
  u16*   Out1   = (u16*)  alloc(4096ull * 768 * 2);    // Acat, rows r=m*8+b at offset 96r
  float* pre    = (float*)alloc(32768ull * 256 * 4);   // gates (enc) / ghh (dec)
  float* xg     = (float*)alloc(32768ull * 256 * 4);
  u16*   zbf    = (u16*)  alloc(32768ull * 64 * 2);
  u16*   hbf    = (u16*)  alloc(32768ull * 64 * 2);
  float* cdec   = (float*)alloc(32768ull * 64 * 4);
  u16*   WT     = (u16*)  alloc(256ull * 96 * 2);
  u16*   WihB   = (u16*)  alloc(256ull * 64 * 2);
  u16*   WhhB   = (u16*)  alloc(256ull * 64 * 2);

  float* zout  = (float*)d_out;                   // [B,N,H] = 2,097,152 floats
  float* recon = (float*)d_out + 2097152;         // [B*N, S] flat

  conv_adj<<<16384, 256, 0, stream>>>(adj, adj_bf);
  build_w <<<  224, 256, 0, stream>>>(W1, W2, Wih, Whh, WT, WihB, WhhB);
  init_pb <<<11776, 256, 0, stream>>>(struc, PB);

  for (int t = 0; t < 12; ++t) {
    pack_x<<<512, 256, 0, stream>>>(X, PB, t);
    gemm_bt64<true ><<<dim3(64, 12), 256, 0, stream>>>(adj_bf, PB, Out1, 4096, 768, 4096);
    gemm_bt64<false><<<dim3(512, 4), 256, 0, stream>>>(Out1, WT, pre, 32768, 256, 96);
    enc_update<<<8192, 256, 0, stream>>>(pre, b1, b2, struc, PB, zout, zbf, t == 11);
  }

  gemm_bt64<false><<<dim3(512, 4), 256, 0, stream>>>(zbf, WihB, xg, 32768, 256, 64);
  zero_dec<<<8192, 256, 0, stream>>>(cdec, hbf);
  for (int s = 0; s < 12; ++s) {
    gemm_bt64<false><<<dim3(512, 4), 256, 0, stream>>>(hbf, WhhB, pre, 32768, 256, 64);
    dec_update<<<512, 256, 0, stream>>>(xg, pre, bih, bhh, D1, bd1, D2, bd2,
                                        cdec, hbf, recon, s);
  }
}

// Round 2
// 1095.905 us; speedup vs baseline: 1.6573x; 1.6573x over previous
//
#include <hip/hip_runtime.h>
#include <cstdint>
#include <cstddef>

// B=8, S=12, N=4096, F=4, H=64
// Encoder stage-1: adj(4096x4096) @ PB^T(768x4096) via 128x128 MFMA tiles,
//   global_load_lds(16B) staging, split-K=4 (bf16 partial slices) + reduce4.
// Encoder stage-2: 64x64-tile GEMM  Out1[32768x96] @ WT^T -> pre, + enc_update.
// Decoder: single fused persistent kernel (12 LSTM steps + MLP, row-independent).

typedef unsigned short u16;
typedef short s8v __attribute__((ext_vector_type(8)));   // 8 x bf16 bits (4 VGPRs)
typedef float f4v __attribute__((ext_vector_type(4)));   // MFMA accumulator

__device__ __forceinline__ u16 f2bf(float x){
  union { float f; uint32_t u; } v; v.f = x;
  uint32_t r = v.u + 0x7FFFu + ((v.u >> 16) & 1u);   // RNE
  return (u16)(r >> 16);
}
__device__ __forceinline__ float bf2f(u16 x){
  union { uint32_t u; float f; } v; v.u = ((uint32_t)x) << 16; return v.f;
}
__device__ __forceinline__ float sigm(float x){ return 1.0f / (1.0f + __expf(-x)); }

typedef const __attribute__((address_space(1))) unsigned int* gp_t;
typedef __attribute__((address_space(3))) unsigned int* lp_t;
__device__ __forceinline__ void glds16(const void* g, void* l){
  __builtin_amdgcn_global_load_lds((gp_t)g, (lp_t)l, 16, 0, 0);
}

// ---------------- Stage-1: 128x128 tile, BK=32, split-K ----------------
// grid (32, 6, 4): mb=bx*128, nb=by*128, K-slice z covers [z*1024, z*1024+1024)
// A = adj_bf [4096][4096], Bt = PB [768][4096], Cpart[z][4096][768] bf16
__global__ __launch_bounds__(256)
void gemm_s1(const u16* __restrict__ A, const u16* __restrict__ Bt,
             u16* __restrict__ Cpart)
{
  __shared__ u16 As[128*32];
  __shared__ u16 Bs[128*32];
  const int t  = threadIdx.x;
  const int l  = t & 63;
  const int w  = t >> 6;
  const int wm = (w >> 1) * 64;
  const int wc = (w & 1) * 64;
  const int mb = blockIdx.x * 128;
  const int nb = blockIdx.y * 128;
  const int k0 = blockIdx.z * 1024;

  f4v acc[4][4];
  #pragma unroll
  for (int i = 0; i < 4; ++i)
    #pragma unroll
    for (int j = 0; j < 4; ++j) acc[i][j] = (f4v)0.0f;

  // staging chunks: c = t (rows 0..63) and c = t+256 (rows 64..127)
  // LDS element offset of chunk c is c*8; content = global k ((c&3)*8) ^ ((row&6)<<2)
  const int r1 = t >> 2;
  const int kE = ((t & 3) * 8) ^ ((r1 & 6) << 2);   // (r1+64)&6 == r1&6
  const u16* a1 = A  + (size_t)(mb + r1)      * 4096 + k0 + kE;
  const u16* a2 = A  + (size_t)(mb + r1 + 64) * 4096 + k0 + kE;
  const u16* b1 = Bt + (size_t)(nb + r1)      * 4096 + k0 + kE;
  const u16* b2 = Bt + (size_t)(nb + r1 + 64) * 4096 + k0 + kE;

  // frag read k-offset (swizzled): same for every frag since (row&6)==(l&6)
  const int kofs = ((l >> 4) * 8) ^ ((l & 6) << 2);
  const int rA = l & 15;

  for (int kk = 0; kk < 1024; kk += 32) {
    glds16(a1 + kk, As + (size_t)t * 8);
    glds16(a2 + kk, As + (size_t)(t + 256) * 8);
    glds16(b1 + kk, Bs + (size_t)t * 8);
    glds16(b2 + kk, Bs + (size_t)(t + 256) * 8);
    __syncthreads();
    s8v af[4], bf[4];
    #pragma unroll
    for (int mt = 0; mt < 4; ++mt)
      af[mt] = *(const s8v*)&As[(wm + mt * 16 + rA) * 32 + kofs];
    #pragma unroll
    for (int nt = 0; nt < 4; ++nt)
      bf[nt] = *(const s8v*)&Bs[(wc + nt * 16 + rA) * 32 + kofs];
    #pragma unroll
    for (int mt = 0; mt < 4; ++mt)
      #pragma unroll
      for (int nt = 0; nt < 4; ++nt)
        acc[mt][nt] = __builtin_amdgcn_mfma_f32_16x16x32_bf16(af[mt], bf[nt], acc[mt][nt], 0, 0, 0);
    __syncthreads();
  }

  u16* Cs = Cpart + (size_t)blockIdx.z * (4096 * 768);
  const int colo = l & 15;
  const int rowo = (l >> 4) * 4;
  #pragma unroll
  for (int mt = 0; mt < 4; ++mt)
    #pragma unroll
    for (int nt = 0; nt < 4; ++nt)
      #pragma unroll
      for (int r = 0; r < 4; ++r) {
        int gr = mb + wm + mt * 16 + rowo + r;
        int gc = nb + wc + nt * 16 + colo;
        Cs[(size_t)gr * 768 + gc] = f2bf(acc[mt][nt][r]);
      }
}

// Out1 = sum of 4 bf16 slices
__global__ __launch_bounds__(256)
void reduce4(const u16* __restrict__ P, u16* __restrict__ O)
{
  const size_t SL = 3145728;   // 4096*768
  size_t i = ((size_t)blockIdx.x * 256 + threadIdx.x) * 8;
  float s[8];
  #pragma unroll
  for (int j = 0; j < 8; ++j) s[j] = 0.0f;
  #pragma unroll
  for (int z = 0; z < 4; ++z) {
    uint4 v = *(const uint4*)(P + z * SL + i);
    uint32_t wds[4] = {v.x, v.y, v.z, v.w};
    #pragma unroll
    for (int q = 0; q < 4; ++q) {
      union { uint32_t u; float f; } lo, hi;
      lo.u = wds[q] << 16; hi.u = wds[q] & 0xFFFF0000u;
      s[2 * q]     += lo.f;
      s[2 * q + 1] += hi.f;
    }
  }
  uint4 o;
  uint32_t* ow = (uint32_t*)&o;
  #pragma unroll
  for (int q = 0; q < 4; ++q)
    ow[q] = (uint32_t)f2bf(s[2 * q]) | ((uint32_t)f2bf(s[2 * q + 1]) << 16);
  *(uint4*)(O + i) = o;
}

// ---------------- Stage-2: 64x64 tile (unchanged from round 0) ----------------
template<bool BF16OUT>
__global__ __launch_bounds__(256)
void gemm_bt64(const u16* __restrict__ A, const u16* __restrict__ Bt,
               void* __restrict__ C, int M, int Ncols, int K)
{
  __shared__ u16 As[64*32];
  __shared__ u16 Bs[64*32];
  const int t  = threadIdx.x;
  const int l  = t & 63;
  const int w  = t >> 6;
  const int wm = (w >> 1) * 32;
  const int wc = (w & 1) * 32;
  const int mb = blockIdx.x * 64;
  const int nb = blockIdx.y * 64;

  f4v acc[2][2];
  #pragma unroll
  for (int i = 0; i < 2; ++i)
    #pragma unroll
    for (int j = 0; j < 2; ++j) acc[i][j] = (f4v)0.0f;

  const int srow = t >> 2;
  const int sko  = (t & 3) * 8;
  const u16* ag = A  + (size_t)(mb + srow) * K + sko;
  const u16* bg = Bt + (size_t)(nb + srow) * K + sko;

  for (int k0 = 0; k0 < K; k0 += 32) {
    uint4 av = *(const uint4*)(ag + k0);
    uint4 bv = *(const uint4*)(bg + k0);
    *(uint4*)&As[t * 8] = av;
    *(uint4*)&Bs[t * 8] = bv;
    __syncthreads();
    s8v af[2], bfr[2];
    #pragma unroll
    for (int mt = 0; mt < 2; ++mt)
      af[mt] = *(const s8v*)&As[(wm + mt*16 + (l & 15)) * 32 + (l >> 4) * 8];
    #pragma unroll
    for (int nt = 0; nt < 2; ++nt)
      bfr[nt] = *(const s8v*)&Bs[(wc + nt*16 + (l & 15)) * 32 + (l >> 4) * 8];
    #pragma unroll
    for (int mt = 0; mt < 2; ++mt)
      #pragma unroll
      for (int nt = 0; nt < 2; ++nt)
        acc[mt][nt] = __builtin_amdgcn_mfma_f32_16x16x32_bf16(af[mt], bfr[nt], acc[mt][nt], 0, 0, 0);
    __syncthreads();
  }

  const int colo = l & 15;
  const int rowo = (l >> 4) * 4;
  #pragma unroll
  for (int mt = 0; mt < 2; ++mt)
    #pragma unroll
    for (int nt = 0; nt < 2; ++nt)
      #pragma unroll
      for (int r = 0; r < 4; ++r) {
        int gr = mb + wm + mt*16 + rowo + r;
        int gc = nb + wc + nt*16 + colo;
        if (BF16OUT) ((u16*)C)[(size_t)gr * Ncols + gc] = f2bf(acc[mt][nt][r]);
        else         ((float*)C)[(size_t)gr * Ncols + gc] = acc[mt][nt][r];
      }
}

__global__ void conv_adj(const float* __restrict__ adj, u16* __restrict__ out){
  size_t i = ((size_t)blockIdx.x * 256 + threadIdx.x) * 4;
  float4 v = *(const float4*)(adj + i);
  ushort4 o; o.x = f2bf(v.x); o.y = f2bf(v.y); o.z = f2bf(v.z); o.w = f2bf(v.w);
  *(ushort4*)(out + i) = o;
}

// WT[j][ch] (256x96): ch 0..3 = W1/W2 x-rows, 4..67 = h-rows, 68..95 = 0. j<192 -> W1, else W2.
__global__ void build_w(const float* __restrict__ W1, const float* __restrict__ W2,
                        const float* __restrict__ Wih, const float* __restrict__ Whh,
                        u16* __restrict__ WT, u16* __restrict__ WihB, u16* __restrict__ WhhB){
  int gid = blockIdx.x * 256 + threadIdx.x;
  if (gid < 24576) {
    int j = gid / 96, ch = gid - j * 96;
    float v = 0.0f;
    if (ch < 68) v = (j < 192) ? W1[(size_t)ch * 192 + j] : W2[(size_t)ch * 64 + (j - 192)];
    WT[gid] = f2bf(v);
  } else if (gid < 24576 + 16384) {
    int q = gid - 24576; WihB[q] = f2bf(Wih[q]);
  } else if (gid < 24576 + 32768) {
    int q = gid - 24576 - 16384; WhhB[q] = f2bf(Whh[q]);
  }
}

// PB rows: b*96 + ch; ch 0..3 = x_t (pack_x), 4..67 = h (init: struc_emb), 68..95 = 0
__global__ void init_pb(const float* __restrict__ struc, u16* __restrict__ PB){
  int gid = blockIdx.x * 256 + threadIdx.x;      // 8*92*4096
  int n = gid & 4095;
  int r = gid >> 12;                             // b*92 + (ch-4)
  int b = r / 92, ch = r - b * 92 + 4;
  float v = (ch < 68) ? struc[(size_t)n * 64 + (ch - 4)] : 0.0f;
  PB[((size_t)(b * 96 + ch)) * 4096 + n] = f2bf(v);
}

__global__ void pack_x(const float* __restrict__ X, u16* __restrict__ PB, int tstep){
  int gid = blockIdx.x * 256 + threadIdx.x;      // 8*4*4096
  int n = gid & 4095;
  int c = (gid >> 12) & 3;
  int b = gid >> 14;
  PB[((size_t)(b * 96 + c)) * 4096 + n] =
      f2bf(X[(((size_t)(b * 12 + tstep)) * 4096 + n) * 4 + c]);
}

// pre[r=(n*8+b)][j 0..255]: j<192 -> W1 gates (pre-b1), 192..255 -> conv (pre-b2)
__global__ __launch_bounds__(256)
void enc_update(const float* __restrict__ pre, const float* __restrict__ b1,
                const float* __restrict__ b2, const float* __restrict__ struc,
                u16* __restrict__ PB, float* __restrict__ zout,
                u16* __restrict__ zbf, int last)
{
  int gid = blockIdx.x * 256 + threadIdx.x;      // 8 * 262144
  int b = gid >> 18;
  int k = gid & 262143;
  int n = k >> 6, hh = k & 63;
  int qi = k + 262144, qo = k + 524288;
  int nf = k  / 192, jf = k  - nf * 192;
  int ni = qi / 192, ji = qi - ni * 192;
  int no = qo / 192, jo = qo - no * 192;
  float fg = sigm(pre[((size_t)nf * 8 + b) * 256 + jf] + b1[jf]);
  float ig = sigm(pre[((size_t)ni * 8 + b) * 256 + ji] + b1[ji]);
  float og = sigm(pre[((size_t)no * 8 + b) * 256 + jo] + b1[jo]);
  float conv = pre[((size_t)n * 8 + b) * 256 + 192 + hh] + b2[hh];
  float c0 = struc[k];
  float c  = fg * c0 + ig * tanhf(conv);
  float hv = og * tanhf(c);
  PB[((size_t)(b * 96 + 4 + hh)) * 4096 + n] = f2bf(hv);
  if (last) {
    zout[(size_t)b * 262144 + k] = hv;
    zbf [(size_t)b * 262144 + k] = f2bf(hv);
  }
}

// ---------------- Fused decoder: 12 LSTM steps + MLP, persistent ----------------
// 512 blocks x 256 thr; block owns rows r0..r0+63 of [B*N=32768].
// Wave w owns rows w*16..w*16+15. MFMA C layout puts all 4 gates of a cell in
// the same lane (cols h, h+64, h+128, h+192 share lane&15) -> register-only cell.
__global__ __launch_bounds__(256)
void dec_fused(const u16* __restrict__ zbf, const u16* __restrict__ WihB,
               const u16* __restrict__ WhhB,
               const float* __restrict__ bih, const float* __restrict__ bhh,
               const float* __restrict__ D1, const float* __restrict__ bd1,
               const float* __restrict__ D2, const float* __restrict__ bd2,
               float* __restrict__ recon)
{
  __shared__ u16  whl[256 * 72];   // Whh, row stride 72 (bank-spread)
  __shared__ u16  hl[64 * 72];     // h, row stride 72
  __shared__ float d1l[64 * 32];
  __shared__ float pdl[64 * 4];
  const int t = threadIdx.x;
  const int l = t & 63;
  const int w = t >> 6;
  const int r0 = blockIdx.x * 64;
  const int rA = l & 15;
  const int kg = (l >> 4) * 8;

  // stage Whh (vectorized 16B) and D1 into LDS
  for (int c = t; c < 2048; c += 256) {
    int j = c >> 3, k8 = (c & 7) * 8;
    *(uint4*)&whl[j * 72 + k8] = *(const uint4*)&WhhB[j * 64 + k8];
  }
  for (int i = t; i < 2048; i += 256) d1l[i] = D1[i];

  // xg = z @ Wih^T + bih + bhh  (kept in registers, MFMA C layout)
  f4v xg[16];
  {
    s8v a0 = *(const s8v*)&zbf[(size_t)(r0 + w * 16 + rA) * 64 + kg];
    s8v a1 = *(const s8v*)&zbf[(size_t)(r0 + w * 16 + rA) * 64 + 32 + kg];
    #pragma unroll
    for (int nt = 0; nt < 16; ++nt) {
      s8v b0 = *(const s8v*)&WihB[(nt * 16 + rA) * 64 + kg];
      s8v b1 = *(const s8v*)&WihB[(nt * 16 + rA) * 64 + 32 + kg];
      f4v a = (f4v)0.0f;
      a = __builtin_amdgcn_mfma_f32_16x16x32_bf16(a0, b0, a, 0, 0, 0);
      a = __builtin_amdgcn_mfma_f32_16x16x32_bf16(a1, b1, a, 0, 0, 0);
      float bb = bih[nt * 16 + rA] + bhh[nt * 16 + rA];
      #pragma unroll
      for (int r = 0; r < 4; ++r) xg[nt][r] = a[r] + bb;
    }
  }
  float cst[16];
  #pragma unroll
  for (int q = 0; q < 16; ++q) cst[q] = 0.0f;
  __syncthreads();   // whl/d1l ready

  for (int s = 0; s < 12; ++s) {
    f4v acc[16];
    #pragma unroll
    for (int nt = 0; nt < 16; ++nt) acc[nt] = xg[nt];
    if (s > 0) {
      s8v a0 = *(const s8v*)&hl[(w * 16 + rA) * 72 + kg];
      s8v a1 = *(const s8v*)&hl[(w * 16 + rA) * 72 + 32 + kg];
      #pragma unroll
      for (int nt = 0; nt < 16; ++nt) {
        s8v b0 = *(const s8v*)&whl[(nt * 16 + rA) * 72 + kg];
        s8v b1 = *(const s8v*)&whl[(nt * 16 + rA) * 72 + 32 + kg];
        acc[nt] = __builtin_amdgcn_mfma_f32_16x16x32_bf16(a0, b0, acc[nt], 0, 0, 0);
        acc[nt] = __builtin_amdgcn_mfma_f32_16x16x32_bf16(a1, b1, acc[nt], 0, 0, 0);
      }
    }
    // cell update: lane holds rows w*16+(l>>4)*4+{0..3} x h in {q*16+(l&15)}
    #pragma unroll
    for (int q = 0; q < 4; ++q)
      #pragma unroll
      for (int r = 0; r < 4; ++r) {
        float i_ = sigm (acc[q     ][r]);
        float f_ = sigm (acc[q + 4 ][r]);
        float g_ = tanhf(acc[q + 8 ][r]);
        float o_ = sigm (acc[q + 12][r]);
        float cc = f_ * cst[q * 4 + r] + i_ * g_;
        cst[q * 4 + r] = cc;
        float hv = o_ * tanhf(cc);
        hl[(w * 16 + (l >> 4) * 4 + r) * 72 + q * 16 + rA] = f2bf(hv);
      }
    __syncthreads();   // hl complete (also guards prior pdl reads)

    // MLP: thread t -> row t&63, jj group (t>>6)*8..+7
    {
      int row = t & 63, jg = t >> 6;
      float m[8];
      #pragma unroll
      for (int j = 0; j < 8; ++j) m[j] = bd1[jg * 8 + j];
      for (int hh = 0; hh < 64; ++hh) {
        float hv = bf2f(hl[row * 72 + hh]);
        #pragma unroll
        for (int j = 0; j < 8; ++j) m[j] += hv * d1l[hh * 32 + jg * 8 + j];
      }
      float pd = 0.0f;
      #pragma unroll
      for (int j = 0; j < 8; ++j) pd += fmaxf(m[j], 0.0f) * D2[jg * 8 + j];
      pdl[row * 4 + jg] = pd;
    }
    __syncthreads();   // pdl complete; all hl reads done
    if (t < 64) {
      float d = pdl[t * 4] + pdl[t * 4 + 1] + pdl[t * 4 + 2] + pdl[t * 4 + 3] + bd2[0];
      recon[(size_t)(r0 + t) * 12 + s] = d;
    }
  }
}

extern "C" void kernel_launch(void* const* d_in, const int* in_sizes, int n_in,
                              void* d_out, int out_size, void* d_ws, size_t ws_size,
                              hipStream_t stream)
{
  (void)in_sizes; (void)n_in; (void)out_size; (void)ws_size;
  const float* X     = (const float*)d_in[0];
  const float* adj   = (const float*)d_in[1];
  const float* struc = (const float*)d_in[2];
  const float* W1    = (const float*)d_in[3];
  const float* b1    = (const float*)d_in[4];
  const float* W2    = (const float*)d_in[5];
  const float* b2    = (const float*)d_in[6];
  const float* Wih   = (const float*)d_in[7];
  const float* Whh   = (const float*)d_in[8];
  const float* bih   = (const float*)d_in[9];
  const float* bhh   = (const float*)d_in[10];
  const float* D1    = (const float*)d_in[11];
  const float* bd1   = (const float*)d_in[12];
  const float* D2    = (const float*)d_in[13];
  const float* bd2   = (const float*)d_in[14];

  char* ws = (char*)d_ws;
  size_t off = 0;
  auto alloc = [&](size_t bytes){ void* p = ws + off; off += (bytes + 255) & ~(size_t)255; return p; };
  u16*   adj_bf = (u16*)  alloc(4096ull * 4096 * 2);     // 33.5 MB
  u16*   PB     = (u16*)  alloc(768ull * 4096 * 2);      // packed B^T [b*96+ch][n]
  u16*   Cpart  = (u16*)  alloc(4ull * 4096 * 768 * 2);  // split-K slices
  u16*   Out1   = (u16*)  alloc(4096ull * 768 * 2);      // reduced stage-1 out
  float* pre    = (float*)alloc(32768ull * 256 * 4);
  u16*   zbf    = (u16*)  alloc(32768ull * 64 * 2);
  u16*   WT     = (u16*)  alloc(256ull * 96 * 2);
  u16*   WihB   = (u16*)  alloc(256ull * 64 * 2);
  u16*   WhhB   = (u16*)  alloc(256ull * 64 * 2);

  float* zout  = (float*)d_out;                   // [B,N,H]
  float* recon = (float*)d_out + 2097152;         // [B*N, S] flat

  conv_adj<<<16384, 256, 0, stream>>>(adj, adj_bf);
  build_w <<<  224, 256, 0, stream>>>(W1, W2, Wih, Whh, WT, WihB, WhhB);
  init_pb <<<11776, 256, 0, stream>>>(struc, PB);

  for (int t = 0; t < 12; ++t) {
    pack_x<<<512, 256, 0, stream>>>(X, PB, t);
    gemm_s1<<<dim3(32, 6, 4), 256, 0, stream>>>(adj_bf, PB, Cpart);
    reduce4<<<1536, 256, 0, stream>>>(Cpart, Out1);
    gemm_bt64<false><<<dim3(512, 4), 256, 0, stream>>>(Out1, WT, pre, 32768, 256, 96);
    enc_update<<<8192, 256, 0, stream>>>(pre, b1, b2, struc, PB, zout, zbf, t == 11);
  }

  dec_fused<<<512, 256, 0, stream>>>(zbf, WihB, WhhB, bih, bhh,
                                     D1, bd1, D2, bd2, recon);
}

// Round 3
// 912.867 us; speedup vs baseline: 1.9897x; 1.2005x over previous
//
#include <hip/hip_runtime.h>
#include <cstdint>
#include <cstddef>

// B=8, S=12, N=4096, F=4, H=64
// x-hoist: AX = adj @ Xall (384 cols, once). Per-step stage-1: adj @ PB(512 h-cols),
//   split-K=4 bf16 slices. Stage-2 fuses the 4-slice reduce + x-cols + GEMM(K=96 pad).
// Decoder: persistent kernel, fast transcendentals, MFMA MLP + shfl butterfly.

typedef unsigned short u16;
typedef short s8v __attribute__((ext_vector_type(8)));   // 8 x bf16 bits (4 VGPRs)
typedef float f4v __attribute__((ext_vector_type(4)));   // MFMA accumulator

__device__ __forceinline__ u16 f2bf(float x){
  union { float f; uint32_t u; } v; v.f = x;
  uint32_t r = v.u + 0x7FFFu + ((v.u >> 16) & 1u);   // RNE
  return (u16)(r >> 16);
}
__device__ __forceinline__ float frcp(float x){ return __builtin_amdgcn_rcpf(x); }
__device__ __forceinline__ float fsig(float x){ return frcp(1.0f + __expf(-x)); }
__device__ __forceinline__ float ftanh(float x){ return 1.0f - 2.0f * frcp(1.0f + __expf(2.0f * x)); }

typedef const __attribute__((address_space(1))) unsigned int* gp_t;
typedef __attribute__((address_space(3))) unsigned int* lp_t;
__device__ __forceinline__ void glds16(const void* g, void* l){
  __builtin_amdgcn_global_load_lds((gp_t)g, (lp_t)l, 16, 0, 0);
}

// ---------------- Stage-1: 128x128 tile, BK=32, split-K=4 ----------------
// C[m][col] partial slices; A [4096][4096], Bt [Ncols][4096]; grid (32, Ncols/128, 4)
__global__ __launch_bounds__(256)
void gemm_s1(const u16* __restrict__ A, const u16* __restrict__ Bt,
             u16* __restrict__ Cpart, int Ncols)
{
  __shared__ u16 As[128*32];
  __shared__ u16 Bs[128*32];
  const int t  = threadIdx.x;
  const int l  = t & 63;
  const int w  = t >> 6;
  const int wm = (w >> 1) * 64;
  const int wc = (w & 1) * 64;
  const int mb = blockIdx.x * 128;
  const int nb = blockIdx.y * 128;
  const int k0 = blockIdx.z * 1024;

  f4v acc[4][4];
  #pragma unroll
  for (int i = 0; i < 4; ++i)
    #pragma unroll
    for (int j = 0; j < 4; ++j) acc[i][j] = (f4v)0.0f;

  const int r1 = t >> 2;
  const int kE = ((t & 3) * 8) ^ ((r1 & 6) << 2);   // XOR bank swizzle
  const u16* a1 = A  + (size_t)(mb + r1)      * 4096 + k0 + kE;
  const u16* a2 = A  + (size_t)(mb + r1 + 64) * 4096 + k0 + kE;
  const u16* b1 = Bt + (size_t)(nb + r1)      * 4096 + k0 + kE;
  const u16* b2 = Bt + (size_t)(nb + r1 + 64) * 4096 + k0 + kE;

  const int kofs = ((l >> 4) * 8) ^ ((l & 6) << 2);
  const int rA = l & 15;

  for (int kk = 0; kk < 1024; kk += 32) {
    glds16(a1 + kk, As + (size_t)t * 8);
    glds16(a2 + kk, As + (size_t)(t + 256) * 8);
    glds16(b1 + kk, Bs + (size_t)t * 8);
    glds16(b2 + kk, Bs + (size_t)(t + 256) * 8);
    __syncthreads();
    s8v af[4], bf[4];
    #pragma unroll
    for (int mt = 0; mt < 4; ++mt)
      af[mt] = *(const s8v*)&As[(wm + mt * 16 + rA) * 32 + kofs];
    #pragma unroll
    for (int nt = 0; nt < 4; ++nt)
      bf[nt] = *(const s8v*)&Bs[(wc + nt * 16 + rA) * 32 + kofs];
    #pragma unroll
    for (int mt = 0; mt < 4; ++mt)
      #pragma unroll
      for (int nt = 0; nt < 4; ++nt)
        acc[mt][nt] = __builtin_amdgcn_mfma_f32_16x16x32_bf16(af[mt], bf[nt], acc[mt][nt], 0, 0, 0);
    __syncthreads();
  }

  u16* Cs = Cpart + (size_t)blockIdx.z * 4096 * Ncols;
  const int colo = l & 15;
  const int rowo = (l >> 4) * 4;
  #pragma unroll
  for (int mt = 0; mt < 4; ++mt)
    #pragma unroll
    for (int nt = 0; nt < 4; ++nt)
      #pragma unroll
      for (int r = 0; r < 4; ++r) {
        int gr = mb + wm + mt * 16 + rowo + r;
        int gc = nb + wc + nt * 16 + colo;
        Cs[(size_t)gr * Ncols + gc] = f2bf(acc[mt][nt][r]);
      }
}

// O[i] = sum_z P[z*SL + i]  (bf16), i in [0, SL)
__global__ __launch_bounds__(256)
void reduceN(const u16* __restrict__ P, u16* __restrict__ O, size_t SL)
{
  size_t i = ((size_t)blockIdx.x * 256 + threadIdx.x) * 8;
  if (i >= SL) return;
  float s[8] = {0,0,0,0,0,0,0,0};
  #pragma unroll
  for (int z = 0; z < 4; ++z) {
    uint4 v = *(const uint4*)(P + z * SL + i);
    uint32_t wd[4] = {v.x, v.y, v.z, v.w};
    #pragma unroll
    for (int q = 0; q < 4; ++q) {
      union { uint32_t u; float f; } lo, hi;
      lo.u = wd[q] << 16; hi.u = wd[q] & 0xFFFF0000u;
      s[2*q] += lo.f; s[2*q+1] += hi.f;
    }
  }
  uint4 o; uint32_t* ow = (uint32_t*)&o;
  #pragma unroll
  for (int q = 0; q < 4; ++q)
    ow[q] = (uint32_t)f2bf(s[2*q]) | ((uint32_t)f2bf(s[2*q+1]) << 16);
  *(uint4*)(O + i) = o;
}

// ---------- Stage-2 fused: (sum 4 AH slices | AX x-cols | pad) @ WT^T -> pre ----------
// A rows r = n*8+b; h-cols 0..63 = AH[z][r*64+hh]; x-cols 64..67 = AX[n][t*32+b*4+f].
// LDS row stride 104 (2-way-free frag reads). grid (512, 4).
__global__ __launch_bounds__(256)
void gemm_s2(const u16* __restrict__ AH, const u16* __restrict__ AXb,
             const u16* __restrict__ WT, float* __restrict__ pre, int tstep)
{
  __shared__ u16 As[64*104];
  __shared__ u16 Bs[64*104];
  const int t = threadIdx.x;
  const int l = t & 63, w = t >> 6;
  const int wm = (w >> 1) * 32, wc = (w & 1) * 32;
  const int mb = blockIdx.x * 64, nb = blockIdx.y * 64;
  const size_t SL = 32768ull * 64;

  // A h-part: 64 rows x 8 octs = 512 chunks, sum 4 slices in fp32
  #pragma unroll
  for (int pass = 0; pass < 2; ++pass) {
    int idx = t + pass * 256;
    int row = idx >> 3, oct = idx & 7;
    size_t base = (size_t)(mb + row) * 64 + oct * 8;
    float s[8] = {0,0,0,0,0,0,0,0};
    #pragma unroll
    for (int z = 0; z < 4; ++z) {
      uint4 v = *(const uint4*)(AH + z * SL + base);
      uint32_t wd[4] = {v.x, v.y, v.z, v.w};
      #pragma unroll
      for (int q = 0; q < 4; ++q) {
        union { uint32_t u; float f; } lo, hi;
        lo.u = wd[q] << 16; hi.u = wd[q] & 0xFFFF0000u;
        s[2*q] += lo.f; s[2*q+1] += hi.f;
      }
    }
    uint4 o; uint32_t* ow = (uint32_t*)&o;
    #pragma unroll
    for (int q = 0; q < 4; ++q)
      ow[q] = (uint32_t)f2bf(s[2*q]) | ((uint32_t)f2bf(s[2*q+1]) << 16);
    *(uint4*)&As[row * 104 + oct * 8] = o;
  }
  // A x-part + zero pad: 64 rows x 4 quads of 8 cols (cols 64..95)
  {
    int row = t >> 2, q = t & 3;
    uint4 o = {0, 0, 0, 0};
    if (q == 0) {
      int r = mb + row, n = r >> 3, b = r & 7;
      const uint32_t* src = (const uint32_t*)(AXb + (size_t)n * 384 + tstep * 32 + b * 4);
      o.x = src[0]; o.y = src[1];
    }
    *(uint4*)&As[row * 104 + 64 + q * 8] = o;
  }
  // B: WT tile rows nb..nb+63, 96 cols
  #pragma unroll
  for (int pass = 0; pass < 3; ++pass) {
    int idx = t + pass * 256;
    if (idx < 768) {
      int row = idx / 12, seg = idx - row * 12;
      *(uint4*)&Bs[row * 104 + seg * 8] = *(const uint4*)(WT + (size_t)(nb + row) * 96 + seg * 8);
    }
  }
  __syncthreads();

  f4v acc[2][2];
  #pragma unroll
  for (int i = 0; i < 2; ++i)
    #pragma unroll
    for (int j = 0; j < 2; ++j) acc[i][j] = (f4v)0.0f;
  const int rA = l & 15, kg = (l >> 4) * 8;
  #pragma unroll
  for (int kc = 0; kc < 3; ++kc) {
    s8v af[2], bf[2];
    #pragma unroll
    for (int mt = 0; mt < 2; ++mt)
      af[mt] = *(const s8v*)&As[(wm + mt * 16 + rA) * 104 + kc * 32 + kg];
    #pragma unroll
    for (int nt = 0; nt < 2; ++nt)
      bf[nt] = *(const s8v*)&Bs[(wc + nt * 16 + rA) * 104 + kc * 32 + kg];
    #pragma unroll
    for (int mt = 0; mt < 2; ++mt)
      #pragma unroll
      for (int nt = 0; nt < 2; ++nt)
        acc[mt][nt] = __builtin_amdgcn_mfma_f32_16x16x32_bf16(af[mt], bf[nt], acc[mt][nt], 0, 0, 0);
  }

  const int colo = l & 15, rowo = (l >> 4) * 4;
  #pragma unroll
  for (int mt = 0; mt < 2; ++mt)
    #pragma unroll
    for (int nt = 0; nt < 2; ++nt)
      #pragma unroll
      for (int r = 0; r < 4; ++r)
        pre[(size_t)(mb + wm + mt * 16 + rowo + r) * 256 + nb + wc + nt * 16 + colo] = acc[mt][nt][r];
}

__global__ void conv_adj(const float* __restrict__ adj, u16* __restrict__ out){
  size_t i = ((size_t)blockIdx.x * 256 + threadIdx.x) * 4;
  float4 v = *(const float4*)(adj + i);
  ushort4 o; o.x = f2bf(v.x); o.y = f2bf(v.y); o.z = f2bf(v.z); o.w = f2bf(v.w);
  *(ushort4*)(out + i) = o;
}

// WT[j][ch]: ch 0..63 = h-rows (W row 4+ch), 64..67 = x-rows (W row ch-64), 68..95 = 0.
// j<192 -> W1 col j; else W2 col j-192. Also WihB, WhhB, D1t[j][hh]=D1[hh][j].
__global__ void build_w(const float* __restrict__ W1, const float* __restrict__ W2,
                        const float* __restrict__ Wih, const float* __restrict__ Whh,
                        const float* __restrict__ D1,
                        u16* __restrict__ WT, u16* __restrict__ WihB,
                        u16* __restrict__ WhhB, u16* __restrict__ D1t){
  int gid = blockIdx.x * 256 + threadIdx.x;
  if (gid < 24576) {
    int j = gid / 96, ch = gid - j * 96;
    float v = 0.0f;
    int rr = (ch < 64) ? (ch + 4) : (ch < 68 ? ch - 64 : -1);
    if (rr >= 0) v = (j < 192) ? W1[(size_t)rr * 192 + j] : W2[(size_t)rr * 64 + (j - 192)];
    WT[gid] = f2bf(v);
  } else if (gid < 40960) {
    int q = gid - 24576; WihB[q] = f2bf(Wih[q]);
  } else if (gid < 57344) {
    int q = gid - 40960; WhhB[q] = f2bf(Whh[q]);
  } else if (gid < 59392) {
    int q = gid - 57344;               // q = j*64 + hh
    int j = q >> 6, hh = q & 63;
    D1t[q] = f2bf(D1[(size_t)hh * 32 + j]);
  }
}

// PB rows r = b*64+hh (512), init from struc_emb
__global__ void init_pb(const float* __restrict__ struc, u16* __restrict__ PB){
  int gid = blockIdx.x * 256 + threadIdx.x;      // 512*4096
  int n = gid & 4095;
  int r = gid >> 12;
  int hh = r & 63;
  PB[(size_t)r * 4096 + n] = f2bf(struc[(size_t)n * 64 + hh]);
}

// Xp[col][n], col = t*32 + b*4 + f  (384 rows)
__global__ void pack_xall(const float* __restrict__ X, u16* __restrict__ Xp){
  int gid = blockIdx.x * 256 + threadIdx.x;      // 384*4096
  int n = gid & 4095;
  int col = gid >> 12;
  int ts = col >> 5, r = col & 31, b = r >> 2, f = r & 3;
  Xp[(size_t)col * 4096 + n] = f2bf(X[(((size_t)(b * 12 + ts)) * 4096 + n) * 4 + f]);
}

// pre[r=(n*8+b)][j 0..255]: j<192 -> W1 gates (pre-b1), 192..255 -> conv (pre-b2)
__global__ __launch_bounds__(256)
void enc_update(const float* __restrict__ pre, const float* __restrict__ b1,
                const float* __restrict__ b2, const float* __restrict__ struc,
                u16* __restrict__ PB, float* __restrict__ zout,
                u16* __restrict__ zbf, int last)
{
  int gid = blockIdx.x * 256 + threadIdx.x;      // 8 * 262144
  int b = gid >> 18;
  int k = gid & 262143;
  int n = k >> 6, hh = k & 63;
  int qi = k + 262144, qo = k + 524288;
  int nf = k  / 192, jf = k  - nf * 192;
  int ni = qi / 192, ji = qi - ni * 192;
  int no = qo / 192, jo = qo - no * 192;
  float fg = fsig(pre[((size_t)nf * 8 + b) * 256 + jf] + b1[jf]);
  float ig = fsig(pre[((size_t)ni * 8 + b) * 256 + ji] + b1[ji]);
  float og = fsig(pre[((size_t)no * 8 + b) * 256 + jo] + b1[jo]);
  float conv = pre[((size_t)n * 8 + b) * 256 + 192 + hh] + b2[hh];
  float c0 = struc[k];
  float c  = fg * c0 + ig * ftanh(conv);
  float hv = og * ftanh(c);
  PB[((size_t)(b * 64 + hh)) * 4096 + n] = f2bf(hv);
  if (last) {
    zout[(size_t)b * 262144 + k] = hv;
    zbf [(size_t)b * 262144 + k] = f2bf(hv);
  }
}

// ---------------- Fused decoder ----------------
// 512 blocks x 256 thr; block owns 64 rows; wave w rows w*16..+15.
// MFMA MLP: hs@D1 via 4 MFMAs, D2-dot via 16-lane shfl_xor butterfly.
__global__ __launch_bounds__(256)
void dec_fused(const u16* __restrict__ zbf, const u16* __restrict__ WihB,
               const u16* __restrict__ WhhB,
               const float* __restrict__ bih, const float* __restrict__ bhh,
               const u16* __restrict__ D1t, const float* __restrict__ bd1,
               const float* __restrict__ D2, const float* __restrict__ bd2,
               float* __restrict__ recon)
{
  __shared__ u16 whl[256 * 72];   // Whh, row stride 72
  __shared__ u16 hl[64 * 72];     // h exchange, row stride 72
  const int t = threadIdx.x;
  const int l = t & 63;
  const int w = t >> 6;
  const int r0 = blockIdx.x * 64;
  const int rA = l & 15;
  const int kg = (l >> 4) * 8;

  for (int c = t; c < 2048; c += 256) {
    int j = c >> 3, k8 = (c & 7) * 8;
    *(uint4*)&whl[j * 72 + k8] = *(const uint4*)&WhhB[j * 64 + k8];
  }

  // xg = z @ Wih^T + bih + bhh (registers, MFMA C layout)
  f4v xg[16];
  {
    s8v a0 = *(const s8v*)&zbf[(size_t)(r0 + w * 16 + rA) * 64 + kg];
    s8v a1 = *(const s8v*)&zbf[(size_t)(r0 + w * 16 + rA) * 64 + 32 + kg];
    #pragma unroll
    for (int nt = 0; nt < 16; ++nt) {
      s8v b0 = *(const s8v*)&WihB[(nt * 16 + rA) * 64 + kg];
      s8v b1 = *(const s8v*)&WihB[(nt * 16 + rA) * 64 + 32 + kg];
      f4v a = (f4v)0.0f;
      a = __builtin_amdgcn_mfma_f32_16x16x32_bf16(a0, b0, a, 0, 0, 0);
      a = __builtin_amdgcn_mfma_f32_16x16x32_bf16(a1, b1, a, 0, 0, 0);
      float bb = bih[nt * 16 + rA] + bhh[nt * 16 + rA];
      #pragma unroll
      for (int r = 0; r < 4; ++r) xg[nt][r] = a[r] + bb;
    }
  }
  // D1 frags + per-lane MLP consts
  s8v d1f[4];
  #pragma unroll
  for (int nt = 0; nt < 2; ++nt)
    #pragma unroll
    for (int kc = 0; kc < 2; ++kc)
      d1f[nt * 2 + kc] = *(const s8v*)&D1t[(nt * 16 + rA) * 64 + kc * 32 + kg];
  const float bd1x = bd1[rA], bd1y = bd1[16 + rA];
  const float d2x = D2[rA], d2y = D2[16 + rA];
  const float bd2v = bd2[0];

  float cst[16];
  #pragma unroll
  for (int q = 0; q < 16; ++q) cst[q] = 0.0f;
  s8v ha0 = (s8v)0, ha1 = (s8v)0;
  __syncthreads();   // whl ready

  for (int s = 0; s < 12; ++s) {
    f4v acc[16];
    #pragma unroll
    for (int nt = 0; nt < 16; ++nt) acc[nt] = xg[nt];
    if (s > 0) {
      #pragma unroll
      for (int nt = 0; nt < 16; ++nt) {
        s8v b0 = *(const s8v*)&whl[(nt * 16 + rA) * 72 + kg];
        s8v b1 = *(const s8v*)&whl[(nt * 16 + rA) * 72 + 32 + kg];
        acc[nt] = __builtin_amdgcn_mfma_f32_16x16x32_bf16(ha0, b0, acc[nt], 0, 0, 0);
        acc[nt] = __builtin_amdgcn_mfma_f32_16x16x32_bf16(ha1, b1, acc[nt], 0, 0, 0);
      }
    }
    // cell update (i,f,g,o torch order); lane rows w*16+(l>>4)*4+r, col q*16+rA
    #pragma unroll
    for (int q = 0; q < 4; ++q)
      #pragma unroll
      for (int r = 0; r < 4; ++r) {
        float i_ = fsig (acc[q     ][r]);
        float f_ = fsig (acc[q + 4 ][r]);
        float g_ = ftanh(acc[q + 8 ][r]);
        float o_ = fsig (acc[q + 12][r]);
        float cc = f_ * cst[q * 4 + r] + i_ * g_;
        cst[q * 4 + r] = cc;
        float hv = o_ * ftanh(cc);
        hl[(w * 16 + (l >> 4) * 4 + r) * 72 + q * 16 + rA] = f2bf(hv);
      }
    __syncthreads();   // hl complete
    ha0 = *(const s8v*)&hl[(w * 16 + rA) * 72 + kg];
    ha1 = *(const s8v*)&hl[(w * 16 + rA) * 72 + 32 + kg];
    // MLP via MFMA: m = hs@D1; relu; dot D2 via butterfly over the 16-lane group
    f4v m0 = (f4v)0.0f, m1 = (f4v)0.0f;
    m0 = __builtin_amdgcn_mfma_f32_16x16x32_bf16(ha0, d1f[0], m0, 0, 0, 0);
    m0 = __builtin_amdgcn_mfma_f32_16x16x32_bf16(ha1, d1f[1], m0, 0, 0, 0);
    m1 = __builtin_amdgcn_mfma_f32_16x16x32_bf16(ha0, d1f[2], m1, 0, 0, 0);
    m1 = __builtin_amdgcn_mfma_f32_16x16x32_bf16(ha1, d1f[3], m1, 0, 0, 0);
    f4v p;
    #pragma unroll
    for (int r = 0; r < 4; ++r)
      p[r] = fmaxf(m0[r] + bd1x, 0.0f) * d2x + fmaxf(m1[r] + bd1y, 0.0f) * d2y;
    #pragma unroll
    for (int mask = 1; mask < 16; mask <<= 1)
      #pragma unroll
      for (int r = 0; r < 4; ++r) p[r] += __shfl_xor(p[r], mask);
    if (rA < 4)
      recon[(size_t)(r0 + w * 16 + (l >> 4) * 4 + rA) * 12 + s] = p[rA] + bd2v;
    __syncthreads();   // all hl reads done before next overwrite
  }
}

extern "C" void kernel_launch(void* const* d_in, const int* in_sizes, int n_in,
                              void* d_out, int out_size, void* d_ws, size_t ws_size,
                              hipStream_t stream)
{
  (void)in_sizes; (void)n_in; (void)out_size; (void)ws_size;
  const float* X     = (const float*)d_in[0];
  const float* adj   = (const float*)d_in[1];
  const float* struc = (const float*)d_in[2];
  const float* W1    = (const float*)d_in[3];
  const float* b1    = (const float*)d_in[4];
  const float* W2    = (const float*)d_in[5];
  const float* b2    = (const float*)d_in[6];
  const float* Wih   = (const float*)d_in[7];
  const float* Whh   = (const float*)d_in[8];
  const float* bih   = (const float*)d_in[9];
  const float* bhh   = (const float*)d_in[10];
  const float* D1    = (const float*)d_in[11];
  const float* bd1   = (const float*)d_in[12];
  const float* D2    = (const float*)d_in[13];
  const float* bd2   = (const float*)d_in[14];

  char* ws = (char*)d_ws;
  size_t off = 0;
  auto alloc = [&](size_t bytes){ void* p = ws + off; off += (bytes + 255) & ~(size_t)255; return p; };
  u16*   adj_bf = (u16*)  alloc(4096ull * 4096 * 2);     // 33.5 MB
  u16*   PB     = (u16*)  alloc(512ull * 4096 * 2);      // h cols [b*64+hh][n]
  u16*   Xp     = (u16*)  alloc(384ull * 4096 * 2);      // x cols [t*32+b*4+f][n]
  u16*   AXb    = (u16*)  alloc(4096ull * 384 * 2);      // adj@X, all steps
  u16*   Cpart  = (u16*)  alloc(4ull * 4096 * 512 * 2);  // split-K slices (also AX tmp)
  float* pre    = (float*)alloc(32768ull * 256 * 4);
  u16*   zbf    = (u16*)  alloc(32768ull * 64 * 2);
  u16*   WT     = (u16*)  alloc(256ull * 96 * 2);
  u16*   WihB   = (u16*)  alloc(256ull * 64 * 2);
  u16*   WhhB   = (u16*)  alloc(256ull * 64 * 2);
  u16*   D1t    = (u16*)  alloc(32ull * 64 * 2);

  float* zout  = (float*)d_out;                   // [B,N,H]
  float* recon = (float*)d_out + 2097152;         // [B*N, S] flat

  conv_adj <<<16384, 256, 0, stream>>>(adj, adj_bf);
  build_w  <<<  232, 256, 0, stream>>>(W1, W2, Wih, Whh, D1, WT, WihB, WhhB, D1t);
  init_pb  <<< 8192, 256, 0, stream>>>(struc, PB);
  pack_xall<<< 6144, 256, 0, stream>>>(X, Xp);
  gemm_s1  <<<dim3(32, 3, 4), 256, 0, stream>>>(adj_bf, Xp, Cpart, 384);
  reduceN  <<<  768, 256, 0, stream>>>(Cpart, AXb, 4096ull * 384);

  for (int t = 0; t < 12; ++t) {
    gemm_s1<<<dim3(32, 4, 4), 256, 0, stream>>>(adj_bf, PB, Cpart, 512);
    gemm_s2<<<dim3(512, 4),   256, 0, stream>>>(Cpart, AXb, WT, pre, t);
    enc_update<<<8192, 256, 0, stream>>>(pre, b1, b2, struc, PB, zout, zbf, t == 11);
  }

  dec_fused<<<512, 256, 0, stream>>>(zbf, WihB, WhhB, bih, bhh,
                                     D1t, bd1, D2, bd2, recon);
}